// Round 13
// baseline (903.816 us; speedup 1.0000x reference)
//
#include <hip/hip_runtime.h>
#include <math.h>
#include <stdint.h>

#define BSZd 32
#define NTOK 243
#define DIMd 544
#define NH 8
#define HDd 68
#define NSEED 17
#define UPDd 1088
#define UCd 136
#define MROWS (BSZd*NTOK)          // 7776
#define BND ((size_t)MROWS*DIMd)   // 4230144
#define QPP 24576
#define KPOFF ((size_t)256*QPP)
#define VTP 20480
#define PBP 65536
#define BUFE (128*32)              // 128-tile LDS buffer
#define BUFE64 (64*32)             // 64-tile LDS buffer
#define BUFA (128*32)              // 256-tile A buffer
#define BUFB (256*32)              // 256-tile B buffer

typedef __bf16 bfx8 __attribute__((ext_vector_type(8)));
typedef __bf16 bfx4 __attribute__((ext_vector_type(4)));
typedef float  fx4  __attribute__((ext_vector_type(4)));

#define GLOAD_LDS(g, l) __builtin_amdgcn_global_load_lds( \
    (__attribute__((address_space(1))) void*)(g), \
    (__attribute__((address_space(3))) void*)(l), 16, 0, 0)

// ========== MFMA core, 128x128 tile, BK=32, 4 waves — double-buffered LDS ==========
__device__ __forceinline__ void mfma_core(const __bf16* __restrict__ A, int lda,
        const __bf16* __restrict__ W, int ldb, int K,
        __bf16* __restrict__ As, __bf16* __restrict__ Bs, fx4 acc[4][4]) {
    const int tid = threadIdx.x;
    const int lane = tid & 63, wave = tid >> 6;
    const int r = lane >> 2, cp = lane & 3;
    const int c = cp ^ (r & 3) ^ ((r >> 2) & 1);
    const __bf16* Ag0 = A + (size_t)(wave * 32 + r) * lda + c * 8;
    const __bf16* Ag1 = Ag0 + (size_t)16 * lda;
    const __bf16* Wg0 = W + (size_t)(wave * 32 + r) * ldb + c * 8;
    const __bf16* Wg1 = Wg0 + (size_t)16 * ldb;
    const int wr0 = (wave * 32) * 32;
    const int wr1 = (wave * 32 + 16) * 32;
    const int fl = lane & 15, q = lane >> 4;
    const int wm = (wave & 1) * 64, wn = (wave >> 1) * 64;
    const int sw = (fl & 3) ^ ((fl >> 2) & 1);
    const int IT = K >> 5;
    GLOAD_LDS(Ag0, As + wr0);
    GLOAD_LDS(Ag1, As + wr1);
    GLOAD_LDS(Wg0, Bs + wr0);
    GLOAD_LDS(Wg1, Bs + wr1);
    for (int kit = 0; kit < IT; kit++) {
        const int p = kit & 1;
        __syncthreads();
        if (kit + 1 < IT) {
            const int np = 1 - p;
            const int off = (kit + 1) * 32;
            GLOAD_LDS(Ag0 + off, As + np * BUFE + wr0);
            GLOAD_LDS(Ag1 + off, As + np * BUFE + wr1);
            GLOAD_LDS(Wg0 + off, Bs + np * BUFE + wr0);
            GLOAD_LDS(Wg1 + off, Bs + np * BUFE + wr1);
        }
        const __bf16* Ab = As + p * BUFE;
        const __bf16* Bb = Bs + p * BUFE;
        bfx8 af[4], bfr[4];
        #pragma unroll
        for (int i = 0; i < 4; i++) {
            int m = wm + i * 16 + fl;
            af[i] = *(const bfx8*)(Ab + (m * 4 + (q ^ sw)) * 8);
            int n = wn + i * 16 + fl;
            bfr[i] = *(const bfx8*)(Bb + (n * 4 + (q ^ sw)) * 8);
        }
        #pragma unroll
        for (int i = 0; i < 4; i++)
            #pragma unroll
            for (int j = 0; j < 4; j++)
                acc[i][j] = __builtin_amdgcn_mfma_f32_16x16x32_bf16(af[i], bfr[j], acc[i][j], 0, 0, 0);
    }
}

// ---------------- fused weight fp32 -> bf16 ---------
struct Cvt8 {
    const float* src[8];
    __bf16* dst[8];
    int nreal[8];
    int rows[8];
    int K[8];
};
__global__ __launch_bounds__(256) void cvt_all(Cvt8 d) {
    int blk = blockIdx.x;
    int seg = 0, base = 0;
    while (seg < 7 && blk - base >= d.rows[seg]) { base += d.rows[seg]; seg++; }
    int n = blk - base;
    int K = d.K[seg];
    __bf16* drow = d.dst[seg] + (size_t)n * K;
    if (n < d.nreal[seg]) {
        const float* srow = d.src[seg] + (size_t)n * K;
        for (int k = threadIdx.x * 4; k < K; k += 1024) {
            float4 v = *(const float4*)(srow + k);
            bfx4 o; o[0]=(__bf16)v.x; o[1]=(__bf16)v.y; o[2]=(__bf16)v.z; o[3]=(__bf16)v.w;
            *(bfx4*)(drow + k) = o;
        }
    } else {
        bfx4 z = {(__bf16)0.f,(__bf16)0.f,(__bf16)0.f,(__bf16)0.f};
        for (int k = threadIdx.x * 4; k < K; k += 1024) *(bfx4*)(drow + k) = z;
    }
}

// ---------------- zero fill ----------------
__global__ __launch_bounds__(256) void zero4(float4* __restrict__ p, int n4) {
    float4 z = make_float4(0.f, 0.f, 0.f, 0.f);
    for (int i = blockIdx.x * 256 + threadIdx.x; i < n4; i += gridDim.x * 256)
        p[i] = z;
}

// ---------------- LayerNorm fp32 -> bf16 ----------------
__global__ __launch_bounds__(256) void ln_kernel(const float* __restrict__ x,
        const float* __restrict__ g, const float* __restrict__ bb, __bf16* __restrict__ out) {
    int row = blockIdx.x;
    const float* xr = x + (size_t)row * DIMd;
    __bf16* orow = out + (size_t)row * DIMd;
    int tid = threadIdx.x;
    float e0 = xr[tid];
    float e1 = xr[tid + 256];
    float e2 = (tid < DIMd - 512) ? xr[tid + 512] : 0.f;
    float s  = e0 + e1 + e2;
    float sq = e0*e0 + e1*e1 + e2*e2;
    __shared__ float sa[4], sb[4];
    for (int off = 32; off; off >>= 1) { s += __shfl_down(s, off, 64); sq += __shfl_down(sq, off, 64); }
    int lane = tid & 63, w = tid >> 6;
    if (lane == 0) { sa[w] = s; sb[w] = sq; }
    __syncthreads();
    if (tid == 0) { sa[0] = sa[0]+sa[1]+sa[2]+sa[3]; sb[0] = sb[0]+sb[1]+sb[2]+sb[3]; }
    __syncthreads();
    s = sa[0]; sq = sb[0];
    float mean = s * (1.f / DIMd);
    float var  = sq * (1.f / DIMd) - mean * mean;
    float rstd = rsqrtf(var + 1e-5f);
    orow[tid]       = (__bf16)((e0 - mean) * rstd * g[tid]       + bb[tid]);
    orow[tid + 256] = (__bf16)((e1 - mean) * rstd * g[tid + 256] + bb[tid + 256]);
    if (tid < DIMd - 512)
        orow[tid + 512] = (__bf16)((e2 - mean) * rstd * g[tid + 512] + bb[tid + 512]);
}

// ---------------- MFMA GEMM (128x128 tile) with XCD-aware swizzle ----------------
template<int ACT, int HAS_BIAS, int HAS_RES, int OUTMODE>
__global__ __launch_bounds__(256) void mgemm(
        const __bf16* __restrict__ A, int lda, const __bf16* __restrict__ W, int ldb,
        const float* __restrict__ bias, const float* __restrict__ res,
        void* __restrict__ Cv, int M, int Mtiles, int Nreal, int K, int Cstride,
        __bf16* __restrict__ qQK, __bf16* __restrict__ qVt) {
    const int L = blockIdx.y * gridDim.x + blockIdx.x;
    const int xcd = L & 7, s = L >> 3;
    const int kk2 = s / gridDim.x, j2 = s - kk2 * gridDim.x;
    const int mt = kk2 * 8 + xcd;
    if (mt >= Mtiles) return;
    const int m0 = mt * 128, n0 = j2 * 128;
    __shared__ __bf16 As[2 * BUFE];
    __shared__ __bf16 Bs[2 * BUFE];
    const int tid = threadIdx.x;
    const int lane = tid & 63, wave = tid >> 6;
    fx4 acc[4][4];
    #pragma unroll
    for (int i = 0; i < 4; i++)
        #pragma unroll
        for (int j = 0; j < 4; j++)
            acc[i][j] = (fx4){0.f, 0.f, 0.f, 0.f};
    mfma_core(A + (size_t)m0 * lda, lda, W + (size_t)n0 * ldb, ldb, K, As, Bs, acc);
    const int fl = lane & 15, q = lane >> 4;
    const int wm = (wave & 1) * 64, wn = (wave >> 1) * 64;
    #pragma unroll
    for (int i = 0; i < 4; i++) {
        #pragma unroll
        for (int v = 0; v < 4; v++) {
            int row = m0 + wm + i * 16 + q * 4 + v;
            if (row >= M) continue;
            #pragma unroll
            for (int j = 0; j < 4; j++) {
                int col = n0 + wn + j * 16 + fl;
                if (col >= Nreal) continue;
                float val = acc[i][j][v];
                if (HAS_BIAS) val += bias[col];
                if (ACT == 1) val = 0.5f * val * (1.f + erff(val * 0.70710678118654752f));
                if (HAS_RES)  val += res[(size_t)row * Cstride + col];
                if (OUTMODE == 2) {
                    int t = col / DIMd, rem = col - t * DIMd;
                    int hh = rem / HDd, hd = rem - hh * HDd;
                    int b = row / NTOK, tok = row - b * NTOK;
                    int bh = b * 8 + hh;
                    if (t == 0)      qQK[(size_t)bh * QPP + tok * 96 + hd] = (__bf16)val;
                    else if (t == 1) qQK[KPOFF + (size_t)bh * QPP + tok * 96 + hd] = (__bf16)val;
                    else             qVt[(size_t)bh * VTP + hd * 256 + tok] = (__bf16)val;
                } else if (OUTMODE == 1) {
                    ((__bf16*)Cv)[(size_t)row * Cstride + col] = (__bf16)val;
                } else {
                    ((float*)Cv)[(size_t)row * Cstride + col] = val;
                }
            }
        }
    }
}

// -------- MFMA GEMM (128x256 tile) — wide-N, double-buffered, XCD swizzle --------
// 32 MFMA per barrier (2x the 128-tile): longer T_iter hides cold-miss latency,
// half the vmcnt-drain events per FLOP. Waves: A rows w*32..+31 (2 loads/lane),
// B rows w*64..+63 (4 loads/lane).
template<int ACT, int HAS_BIAS, int HAS_RES, int OUTMODE>
__global__ __launch_bounds__(256) void mgemm256(
        const __bf16* __restrict__ A, int lda, const __bf16* __restrict__ W, int ldb,
        const float* __restrict__ bias, const float* __restrict__ res,
        void* __restrict__ Cv, int M, int Mtiles, int Nreal, int K, int Cstride,
        __bf16* __restrict__ qQK, __bf16* __restrict__ qVt) {
    const int L = blockIdx.y * gridDim.x + blockIdx.x;
    const int xcd = L & 7, s = L >> 3;
    const int kk2 = s / gridDim.x, j2 = s - kk2 * gridDim.x;
    const int mt = kk2 * 8 + xcd;
    if (mt >= Mtiles) return;
    const int m0 = mt * 128, n0 = j2 * 256;
    __shared__ __bf16 As[2 * BUFA];
    __shared__ __bf16 Bs[2 * BUFB];
    const int tid = threadIdx.x, lane = tid & 63, wave = tid >> 6;
    const int r = lane >> 2, cp = lane & 3;
    const int c = cp ^ (r & 3) ^ ((r >> 2) & 1);
    const __bf16* Ag0 = A + (size_t)(m0 + wave * 32 + r) * lda + c * 8;
    const __bf16* Ag1 = Ag0 + (size_t)16 * lda;
    const __bf16* Wg0 = W + (size_t)(n0 + wave * 64 + r) * ldb + c * 8;
    const __bf16* Wg1 = Wg0 + (size_t)16 * ldb;
    const __bf16* Wg2 = Wg0 + (size_t)32 * ldb;
    const __bf16* Wg3 = Wg0 + (size_t)48 * ldb;
    const int ar0 = (wave * 32) * 32, ar1 = ar0 + 16 * 32;
    const int br0 = (wave * 64) * 32, br1 = br0 + 16 * 32, br2 = br0 + 32 * 32, br3 = br0 + 48 * 32;
    const int fl = lane & 15, q = lane >> 4;
    const int wm = (wave & 1) * 64, wn = (wave >> 1) * 128;
    const int sw = (fl & 3) ^ ((fl >> 2) & 1);
    const int IT = K >> 5;
    fx4 acc[4][8];
    #pragma unroll
    for (int i = 0; i < 4; i++)
        #pragma unroll
        for (int j = 0; j < 8; j++)
            acc[i][j] = (fx4){0.f, 0.f, 0.f, 0.f};
    GLOAD_LDS(Ag0, As + ar0);
    GLOAD_LDS(Ag1, As + ar1);
    GLOAD_LDS(Wg0, Bs + br0);
    GLOAD_LDS(Wg1, Bs + br1);
    GLOAD_LDS(Wg2, Bs + br2);
    GLOAD_LDS(Wg3, Bs + br3);
    for (int kit = 0; kit < IT; kit++) {
        const int p = kit & 1;
        __syncthreads();
        if (kit + 1 < IT) {
            const int np = 1 - p;
            const int off = (kit + 1) * 32;
            GLOAD_LDS(Ag0 + off, As + np * BUFA + ar0);
            GLOAD_LDS(Ag1 + off, As + np * BUFA + ar1);
            GLOAD_LDS(Wg0 + off, Bs + np * BUFB + br0);
            GLOAD_LDS(Wg1 + off, Bs + np * BUFB + br1);
            GLOAD_LDS(Wg2 + off, Bs + np * BUFB + br2);
            GLOAD_LDS(Wg3 + off, Bs + np * BUFB + br3);
        }
        const __bf16* Ab = As + p * BUFA;
        const __bf16* Bb = Bs + p * BUFB;
        bfx8 af[4], bfr[8];
        #pragma unroll
        for (int i = 0; i < 4; i++) {
            int m = wm + i * 16 + fl;
            af[i] = *(const bfx8*)(Ab + (m * 4 + (q ^ sw)) * 8);
        }
        #pragma unroll
        for (int j = 0; j < 8; j++) {
            int n = wn + j * 16 + fl;
            bfr[j] = *(const bfx8*)(Bb + (n * 4 + (q ^ sw)) * 8);
        }
        #pragma unroll
        for (int i = 0; i < 4; i++)
            #pragma unroll
            for (int j = 0; j < 8; j++)
                acc[i][j] = __builtin_amdgcn_mfma_f32_16x16x32_bf16(af[i], bfr[j], acc[i][j], 0, 0, 0);
    }
    #pragma unroll
    for (int i = 0; i < 4; i++) {
        #pragma unroll
        for (int v = 0; v < 4; v++) {
            int row = m0 + wm + i * 16 + q * 4 + v;
            if (row >= M) continue;
            #pragma unroll
            for (int j = 0; j < 8; j++) {
                int col = n0 + wn + j * 16 + fl;
                if (col >= Nreal) continue;
                float val = acc[i][j][v];
                if (HAS_BIAS) val += bias[col];
                if (ACT == 1) val = 0.5f * val * (1.f + erff(val * 0.70710678118654752f));
                if (HAS_RES)  val += res[(size_t)row * Cstride + col];
                if (OUTMODE == 2) {
                    int t = col / DIMd, rem = col - t * DIMd;
                    int hh = rem / HDd, hd = rem - hh * HDd;
                    int b = row / NTOK, tok = row - b * NTOK;
                    int bh = b * 8 + hh;
                    if (t == 0)      qQK[(size_t)bh * QPP + tok * 96 + hd] = (__bf16)val;
                    else if (t == 1) qQK[KPOFF + (size_t)bh * QPP + tok * 96 + hd] = (__bf16)val;
                    else             qVt[(size_t)bh * VTP + hd * 256 + tok] = (__bf16)val;
                } else if (OUTMODE == 1) {
                    ((__bf16*)Cv)[(size_t)row * Cstride + col] = (__bf16)val;
                } else {
                    ((float*)Cv)[(size_t)row * Cstride + col] = val;
                }
            }
        }
    }
}

// ---------- MFMA GEMM (64x64 tile) — high-occupancy, double-buffered LDS ----------
template<int ACT, int HAS_BIAS, int HAS_RES, int OUT_BF16>
__global__ __launch_bounds__(256) void mgemm64(
        const __bf16* __restrict__ A, int lda, const __bf16* __restrict__ W, int ldb,
        const float* __restrict__ bias, const float* __restrict__ res,
        void* __restrict__ Cv, int M, int Mtiles, int Nreal, int K, int Cstride) {
    const int L = blockIdx.y * gridDim.x + blockIdx.x;
    const int xcd = L & 7, s = L >> 3;
    const int kk2 = s / gridDim.x, j2 = s - kk2 * gridDim.x;
    const int mt = kk2 * 8 + xcd;
    if (mt >= Mtiles) return;
    const int m0 = mt * 64, n0 = j2 * 64;
    __shared__ __bf16 As[2 * BUFE64];
    __shared__ __bf16 Bs[2 * BUFE64];
    const int tid = threadIdx.x, lane = tid & 63, w = tid >> 6;
    const int r = lane >> 2, cp = lane & 3;
    const int c = cp ^ (r & 3);
    const __bf16* G0;
    int ld, wro;
    int isA = (w < 2);
    if (isA) { ld = lda; G0 = A + (size_t)(m0 + w * 32 + r) * lda + c * 8; wro = (w * 32) * 32; }
    else     { ld = ldb; G0 = W + (size_t)(n0 + (w - 2) * 32 + r) * ldb + c * 8; wro = ((w - 2) * 32) * 32; }
    const __bf16* G1 = G0 + (size_t)16 * ld;
    __bf16* base0 = isA ? As : Bs;
    const int wro1 = wro + 16 * 32;
    const int fl = lane & 15, q = lane >> 4;
    const int wm = (w & 1) * 32, wn = (w >> 1) * 32;
    const int sw = fl & 3;
    const int IT = K >> 5;
    fx4 acc[2][2];
    #pragma unroll
    for (int i = 0; i < 2; i++)
        #pragma unroll
        for (int j = 0; j < 2; j++)
            acc[i][j] = (fx4){0.f, 0.f, 0.f, 0.f};
    GLOAD_LDS(G0, base0 + wro);
    GLOAD_LDS(G1, base0 + wro1);
    for (int kit = 0; kit < IT; kit++) {
        const int p = kit & 1;
        __syncthreads();
        if (kit + 1 < IT) {
            const int np = 1 - p;
            const int off = (kit + 1) * 32;
            GLOAD_LDS(G0 + off, base0 + np * BUFE64 + wro);
            GLOAD_LDS(G1 + off, base0 + np * BUFE64 + wro1);
        }
        const __bf16* Ab = As + p * BUFE64;
        const __bf16* Bb = Bs + p * BUFE64;
        bfx8 af[2], bfr[2];
        #pragma unroll
        for (int i = 0; i < 2; i++) {
            int m = wm + i * 16 + fl;
            af[i] = *(const bfx8*)(Ab + (m * 4 + (q ^ sw)) * 8);
            int n = wn + i * 16 + fl;
            bfr[i] = *(const bfx8*)(Bb + (n * 4 + (q ^ sw)) * 8);
        }
        #pragma unroll
        for (int i = 0; i < 2; i++)
            #pragma unroll
            for (int j = 0; j < 2; j++)
                acc[i][j] = __builtin_amdgcn_mfma_f32_16x16x32_bf16(af[i], bfr[j], acc[i][j], 0, 0, 0);
    }
    #pragma unroll
    for (int i = 0; i < 2; i++)
        #pragma unroll
        for (int v = 0; v < 4; v++) {
            int row = m0 + wm + i * 16 + q * 4 + v;
            if (row >= M) continue;
            #pragma unroll
            for (int j = 0; j < 2; j++) {
                int col = n0 + wn + j * 16 + fl;
                if (col >= Nreal) continue;
                float val = acc[i][j][v];
                if (HAS_BIAS) val += bias[col];
                if (ACT == 1) val = 0.5f * val * (1.f + erff(val * 0.70710678118654752f));
                if (HAS_RES)  val += res[(size_t)row * Cstride + col];
                if (OUT_BF16) ((__bf16*)Cv)[(size_t)row * Cstride + col] = (__bf16)val;
                else          ((float*)Cv)[(size_t)row * Cstride + col] = val;
            }
        }
}

// ---------------- fp32 GEMM for tiny seed matmuls (M=17) ----------------
__global__ __launch_bounds__(256) void gemm32_kernel(
        const float* __restrict__ A, const float* __restrict__ W,
        const float* __restrict__ bias, float* __restrict__ C, int M, int Nn, int K) {
    __shared__ __align__(16) float As[16][68];
    __shared__ __align__(16) float Ws[16][68];
    int tid = threadIdx.x;
    int tx = tid & 15, ty = tid >> 4;
    int m0 = blockIdx.y * 64, n0 = blockIdx.x * 64;
    float acc[4][4] = {};
    int lr = tid >> 2, lk = (tid & 3) << 2;
    for (int k0 = 0; k0 < K; k0 += 16) {
        float4 av = make_float4(0.f,0.f,0.f,0.f), wv = make_float4(0.f,0.f,0.f,0.f);
        int gm = m0 + lr, gn = n0 + lr, gk = k0 + lk;
        if (gm < M)  av = *(const float4*)(A + (size_t)gm * K + gk);
        if (gn < Nn) wv = *(const float4*)(W + (size_t)gn * K + gk);
        __syncthreads();
        As[lk+0][lr]=av.x; As[lk+1][lr]=av.y; As[lk+2][lr]=av.z; As[lk+3][lr]=av.w;
        Ws[lk+0][lr]=wv.x; Ws[lk+1][lr]=wv.y; Ws[lk+2][lr]=wv.z; Ws[lk+3][lr]=wv.w;
        __syncthreads();
        #pragma unroll
        for (int kk = 0; kk < 16; kk++) {
            float4 a4 = *(const float4*)&As[kk][ty << 2];
            float4 b4 = *(const float4*)&Ws[kk][tx << 2];
            float ar[4] = {a4.x, a4.y, a4.z, a4.w};
            float br[4] = {b4.x, b4.y, b4.z, b4.w};
            #pragma unroll
            for (int i = 0; i < 4; i++)
                #pragma unroll
                for (int j = 0; j < 4; j++)
                    acc[i][j] = fmaf(ar[i], br[j], acc[i][j]);
        }
    }
    #pragma unroll
    for (int i = 0; i < 4; i++) {
        int gm = m0 + (ty << 2) + i;
        if (gm >= M) continue;
        #pragma unroll
        for (int j = 0; j < 4; j++) {
            int gn = n0 + (tx << 2) + j;
            if (gn >= Nn) continue;
            C[(size_t)gm * Nn + gn] = acc[i][j] + bias[gn];
        }
    }
}

// ================= ATTENTION kernel A: E = exp(QK^T*scale+bias), row sums =========
__global__ __launch_bounds__(256) void attn_escore(const __bf16* __restrict__ Qp,
        const float* __restrict__ bt, __bf16* __restrict__ Pb, float* __restrict__ rs) {
    __shared__ __bf16 Qs[128 * 96];
    __shared__ __bf16 Ks[256 * 96];
    __shared__ float sumb[128 * 2];
    const int mh = blockIdx.x, bh = blockIdx.y, h = bh & 7;
    const int tid = threadIdx.x, lane = tid & 63, w = tid >> 6;
    const int fl = lane & 15, q = lane >> 4;
    const int wm = (w & 1) * 64, wn = (w >> 1) * 128;
    const __bf16* Qg = Qp + (size_t)bh * QPP + (size_t)mh * 128 * 96;
    const __bf16* Kg = Qp + KPOFF + (size_t)bh * QPP;
    #pragma unroll
    for (int it = 0; it < 6; it++) {
        int Lc = (w * 6 + it) * 64 + lane;
        int r = Lc / 12, sl = Lc - r * 12, c = sl ^ (r & 3);
        GLOAD_LDS(Qg + r * 96 + c * 8, Qs + Lc * 8);
    }
    #pragma unroll
    for (int it = 0; it < 12; it++) {
        int Lc = (w * 12 + it) * 64 + lane;
        int r = Lc / 12, sl = Lc - r * 12, c = sl ^ (r & 3);
        GLOAD_LDS(Kg + r * 96 + c * 8, Ks + Lc * 8);
    }
    __syncthreads();
    fx4 acc[4][8];
    #pragma unroll
    for (int i = 0; i < 4; i++)
        #pragma unroll
        for (int jj = 0; jj < 8; jj++)
            acc[i][jj] = (fx4){0.f, 0.f, 0.f, 0.f};
    #pragma unroll
    for (int kk = 0; kk < 3; kk++) {
        bfx8 af[4], bfr[8];
        #pragma unroll
        for (int i = 0; i < 4; i++) {
            int rA = wm + i * 16 + fl, cA = kk * 4 + q;
            af[i] = *(const bfx8*)(Qs + (rA * 12 + (cA ^ (rA & 3))) * 8);
        }
        #pragma unroll
        for (int jj = 0; jj < 8; jj++) {
            int rB = wn + jj * 16 + fl, cB = kk * 4 + q;
            bfr[jj] = *(const bfx8*)(Ks + (rB * 12 + (cB ^ (rB & 3))) * 8);
        }
        #pragma unroll
        for (int i = 0; i < 4; i++)
            #pragma unroll
            for (int jj = 0; jj < 8; jj++)
                acc[i][jj] = __builtin_amdgcn_mfma_f32_16x16x32_bf16(af[i], bfr[jj], acc[i][jj], 0, 0, 0);
    }
    const float scale = 0.121267812518166f;
    const float* btr = bt + h * (2 * NTOK - 1);
    __bf16* Pp = Pb + (size_t)bh * PBP + (size_t)mh * 128 * 256;
    #pragma unroll
    for (int i = 0; i < 4; i++)
        #pragma unroll
        for (int v = 0; v < 4; v++) {
            int lr = wm + i * 16 + q * 4 + v;
            int gm = mh * 128 + lr;
            float sm = 0.f;
            #pragma unroll
            for (int jj = 0; jj < 8; jj++) {
                int gn = wn + jj * 16 + fl;
                float e = 0.f;
                if (gm < NTOK && gn < NTOK)
                    e = expf(acc[i][jj][v] * scale + btr[gm - gn + NTOK - 1]);
                acc[i][jj][v] = e;
                sm += e;
                Pp[(size_t)lr * 256 + gn] = (__bf16)e;
            }
            #pragma unroll
            for (int msk = 1; msk < 16; msk <<= 1)
                sm += __shfl_xor(sm, msk, 64);
            if (fl == 0) sumb[lr * 2 + (w >> 1)] = sm;
        }
    __syncthreads();
    if (tid < 128)
        rs[(size_t)bh * 256 + mh * 128 + tid] = sumb[tid * 2] + sumb[tid * 2 + 1];
}

// ================= ATTENTION kernel B: O = (E @ V) / rowsum =================
__global__ __launch_bounds__(256) void attn_pv2(const __bf16* __restrict__ Pb,
        const __bf16* __restrict__ Vt, const float* __restrict__ rs,
        __bf16* __restrict__ o) {
    __shared__ __bf16 As[2 * BUFE];
    __shared__ __bf16 Bs[2 * BUFE];
    const int mt = blockIdx.x, bh = blockIdx.y, b = bh >> 3, h = bh & 7;
    const int tid = threadIdx.x, lane = tid & 63, wave = tid >> 6;
    fx4 acc[4][4];
    #pragma unroll
    for (int i = 0; i < 4; i++)
        #pragma unroll
        for (int j = 0; j < 4; j++)
            acc[i][j] = (fx4){0.f, 0.f, 0.f, 0.f};
    mfma_core(Pb + (size_t)bh * PBP + (size_t)mt * 128 * 256, 256,
              Vt + (size_t)bh * VTP, 256, 256, As, Bs, acc);
    const int fl = lane & 15, q = lane >> 4;
    const int wm = (wave & 1) * 64, wn = (wave >> 1) * 64;
    #pragma unroll
    for (int i = 0; i < 4; i++)
        #pragma unroll
        for (int v = 0; v < 4; v++) {
            int gm = mt * 128 + wm + i * 16 + q * 4 + v;
            if (gm >= NTOK) continue;
            float inv = 1.f / rs[(size_t)bh * 256 + gm];
            #pragma unroll
            for (int j = 0; j < 4; j++) {
                int col = wn + j * 16 + fl;
                if (col >= HDd) continue;
                o[((size_t)(b * NTOK + gm)) * DIMd + h * HDd + col] = (__bf16)(acc[i][j][v] * inv);
            }
        }
}

// ---------------- seed scatters ----------------
__global__ __launch_bounds__(256) void scatter_s0big(const float* __restrict__ S0f,
        __bf16* __restrict__ W) {
    int hn = blockIdx.x;
    __bf16* row = W + (size_t)hn * UPDd;
    int h = hn / NSEED, n = hn - h * NSEED;
    for (int j = threadIdx.x; j < UPDd; j += 256) {
        __bf16 v = (__bf16)0.f;
        if (hn < 136 && (j / UCd) == h) v = (__bf16)S0f[(size_t)n * UPDd + j];
        row[j] = v;
    }
}

__global__ __launch_bounds__(256) void scatter_s1bigT(const float* __restrict__ S1f,
        __bf16* __restrict__ W) {
    int j = blockIdx.x;
    __bf16* row = W + (size_t)j * 160;
    int hj = j / UCd;
    int t = threadIdx.x;
    if (t < 160) {
        __bf16 v = (__bf16)0.f;
        if (j < UPDd && t < 136) {
            int h = t / NSEED, n = t - h * NSEED;
            if (h == hj) v = (__bf16)S1f[(size_t)n * UPDd + j];
        }
        row[t] = v;
    }
}

// seed: column softmax over f
__global__ __launch_bounds__(256) void seed_softmax2(float* __restrict__ a2) {
    int col = blockIdx.x, b = blockIdx.y;
    float* base = a2 + (size_t)b * NTOK * 136 + col;
    int f = threadIdx.x;
    __shared__ float rbuf[4];
    float v = (f < NTOK) ? base[(size_t)f * 136] : -1e30f;
    float m = v;
    for (int off = 32; off; off >>= 1) m = fmaxf(m, __shfl_down(m, off, 64));
    int lane = f & 63, w = f >> 6;
    if (lane == 0) rbuf[w] = m;
    __syncthreads();
    m = fmaxf(fmaxf(rbuf[0], rbuf[1]), fmaxf(rbuf[2], rbuf[3]));
    float e = (f < NTOK) ? expf(v - m) : 0.f;
    float s = e;
    for (int off = 32; off; off >>= 1) s += __shfl_down(s, off, 64);
    __syncthreads();
    if (lane == 0) rbuf[w] = s;
    __syncthreads();
    float denom = rbuf[0] + rbuf[1] + rbuf[2] + rbuf[3];
    if (f < NTOK) base[(size_t)f * 136] = e / denom;
}

__global__ void zero_kernel(float* p, int n) {
    int i = blockIdx.x * blockDim.x + threadIdx.x;
    if (i < n) p[i] = 0.f;
}

// seed: renorm over n per (b,f) -> bf16 a2b, per-b mean partials
__global__ __launch_bounds__(256) void seed_renorm(const float* __restrict__ a2,
        __bf16* __restrict__ a2b, float* __restrict__ part) {
    int f = blockIdx.x, b = blockIdx.y;
    int t = threadIdx.x;
    __shared__ float vals[136];
    __shared__ float hinv[8];
    __shared__ float nsum[NSEED];
    if (t < NSEED) nsum[t] = 0.f;
    const float* arow = a2 + ((size_t)(b * NTOK + f)) * 136;
    if (t < 136) vals[t] = arow[t];
    __syncthreads();
    if (t < 8) {
        float s = 0.f;
        #pragma unroll
        for (int n = 0; n < NSEED; n++) s += vals[t * NSEED + n];
        hinv[t] = 1.f / (1e-7f + s);
    }
    __syncthreads();
    __bf16* brow = a2b + ((size_t)(b * NTOK + f)) * 160;
    if (t < 160) {
        if (t < 136) {
            float wv = vals[t] * hinv[t / NSEED];
            brow[t] = (__bf16)wv;
            atomicAdd(&nsum[t % NSEED], wv);
        } else brow[t] = (__bf16)0.f;
    }
    __syncthreads();
    if (t < NSEED) atomicAdd(&part[b * NSEED + t], nsum[t]);
}

__global__ void mean_final(const float* __restrict__ part, float* __restrict__ mean_attn) {
    int n = threadIdx.x;
    if (n < NSEED) {
        float s = 0.f;
        for (int b = 0; b < BSZd; b++) s += part[b * NSEED + n];
        mean_attn[n] = s * (1.f / (BSZd * NH * NTOK));
    }
}

extern "C" void kernel_launch(void* const* d_in, const int* in_sizes, int n_in,
                              void* d_out, int out_size, void* d_ws, size_t ws_size,
                              hipStream_t stream) {
    (void)in_sizes; (void)n_in; (void)out_size; (void)ws_size;
    const float* x       = (const float*)d_in[0];
    const float* seed    = (const float*)d_in[1];
    const float* ln1_g   = (const float*)d_in[2];
    const float* ln1_b   = (const float*)d_in[3];
    const float* w_qkv   = (const float*)d_in[4];
    const float* w_proj  = (const float*)d_in[5];
    const float* b_proj  = (const float*)d_in[6];
    const float* b_table = (const float*)d_in[7];
    const float* ln2_g   = (const float*)d_in[8];
    const float* ln2_b   = (const float*)d_in[9];
    const float* mlp_w1  = (const float*)d_in[10];
    const float* mlp_b1  = (const float*)d_in[11];
    const float* mlp_w2  = (const float*)d_in[12];
    const float* mlp_b2  = (const float*)d_in[13];
    const float* eln1_g  = (const float*)d_in[14];
    const float* eln1_b  = (const float*)d_in[15];
    const float* w_trans = (const float*)d_in[16];
    const float* b_trans = (const float*)d_in[17];
    const float* w0      = (const float*)d_in[18];
    const float* b0      = (const float*)d_in[19];
    const float* w1      = (const float*)d_in[20];
    const float* b1      = (const float*)d_in[21];
    const float* w_proj2 = (const float*)d_in[22];
    const float* b_proj2 = (const float*)d_in[23];
    const float* eln2_g  = (const float*)d_in[24];
    const float* eln2_b  = (const float*)d_in[25];
    const float* emlp_w1 = (const float*)d_in[26];
    const float* emlp_b1 = (const float*)d_in[27];
    const float* emlp_w2 = (const float*)d_in[28];
    const float* emlp_b2 = (const float*)d_in[29];

    // ---- workspace layout (bytes) ----
    char* wsb = (char*)d_ws;
    __bf16* Wq  = (__bf16*)(wsb);               // [1664][544]
    __bf16* Wp  = (__bf16*)(wsb + 1810432);     // [640][544]
    __bf16* Wm1 = (__bf16*)(wsb + 2506752);     // [2176][544]
    __bf16* Wm2 = (__bf16*)(wsb + 4874240);     // [640][2176]
    __bf16* Wt  = (__bf16*)(wsb + 7659520);     // [1152][544]
    __bf16* Wp2 = (__bf16*)(wsb + 8912896);     // [640][1088]
    __bf16* We1 = (__bf16*)(wsb + 10305536);    // [1152][544]
    __bf16* We2 = (__bf16*)(wsb + 11558912);    // [640][1088]
    __bf16* Abf = (__bf16*)(wsb + 12951552);    // [7808][544]
    float*  F1  = (float*) (wsb + 21446656);    // [7776][544] fp32
    float*  F2  = (float*) (wsb + 38367232);    // [7776][544] fp32
    char*   RegBig = wsb + 55287808;            // 33,978,368 B
    char*   RegS   = wsb + 89266176;            // 15,178,752 B
    // attention overlays:
    __bf16* Qp  = (__bf16*)RegBig;              // Q/K panels
    __bf16* Pb  = (__bf16*)F1;                  // E panels (F1+F2)
    __bf16* Vt  = (__bf16*)RegS;                // V panels (10.49MB)
    float*  rsb = (float*)(RegS + 10485760);    // rowsums
    // other phase overlays:
    __bf16* Tb   = (__bf16*)RegBig;             // [7808][2176]
    __bf16* XU   = (__bf16*)RegBig;             // [7776][1088]
    __bf16* O2   = (__bf16*)(RegBig + 16920576);// [7808][1088]
    __bf16* T2   = (__bf16*)RegBig;             // [7808][1088]
    float*  a2    = (float*)RegS;               // [7776][136]
    __bf16* a2b   = (__bf16*)(RegS + 4230144);  // [7808][160]
    float*  S0f   = (float*)(RegS + 6728704);
    float*  S1f   = (float*)(RegS + 6802688);
    __bf16* S0big = (__bf16*)(RegS + 6876672);  // [256][1088]
    __bf16* S1bigT= (__bf16*)(RegS + 7433728);  // [1152][160]
    float*  mean_part = (float*)(RegS + 7802368);
    float* xout = (float*)d_out;
    float* mean_attn = xout + BND;

    dim3 blk(256);
    // 0) fused weight conversion
    Cvt8 cd;
    cd.src[0]=w_qkv;  cd.dst[0]=Wq;  cd.nreal[0]=1632; cd.rows[0]=1664; cd.K[0]=544;
    cd.src[1]=w_proj; cd.dst[1]=Wp;  cd.nreal[1]=544;  cd.rows[1]=640;  cd.K[1]=544;
    cd.src[2]=mlp_w1; cd.dst[2]=Wm1; cd.nreal[2]=2176; cd.rows[2]=2176; cd.K[2]=544;
    cd.src[3]=mlp_w2; cd.dst[3]=Wm2; cd.nreal[3]=544;  cd.rows[3]=640;  cd.K[3]=2176;
    cd.src[4]=w_trans;cd.dst[4]=Wt;  cd.nreal[4]=1088; cd.rows[4]=1152; cd.K[4]=544;
    cd.src[5]=w_proj2;cd.dst[5]=Wp2; cd.nreal[5]=544;  cd.rows[5]=640;  cd.K[5]=1088;
    cd.src[6]=emlp_w1;cd.dst[6]=We1; cd.nreal[6]=1088; cd.rows[6]=1152; cd.K[6]=544;
    cd.src[7]=emlp_w2;cd.dst[7]=We2; cd.nreal[7]=544;  cd.rows[7]=640;  cd.K[7]=1088;
    cvt_all<<<8704, blk, 0, stream>>>(cd);
    // 0b) zero Q/K and V panels (pads)
    zero4<<<1024, blk, 0, stream>>>((float4*)Qp, 1572864);
    zero4<<<1024, blk, 0, stream>>>((float4*)Vt, 655360);
    // 1) h = LN1(x)
    ln_kernel<<<MROWS, blk, 0, stream>>>(x, ln1_g, ln1_b, Abf);
    // 2) qkv -> Qp/Kp/Vt panels   [256-wide tile: 7 n-tiles]
    mgemm256<0,0,0,2><<<dim3(7,64), blk, 0, stream>>>(Abf, 544, Wq, 544, nullptr, nullptr, nullptr, MROWS, 61, 1632, 544, 0, Qp, Vt);
    // 3) attention: E-score + PV
    attn_escore<<<dim3(2,256), blk, 0, stream>>>(Qp, b_table, Pb, rsb);
    attn_pv2<<<dim3(2,256), blk, 0, stream>>>(Pb, Vt, rsb, Abf);
    // 4) x1 = x + o @ w_proj^T + b_proj   [64-tile dbuf]
    mgemm64<0,1,1,0><<<dim3(9,128), blk, 0, stream>>>(Abf, 544, Wp, 544, b_proj, x, F1, MROWS, 122, 544, 544, 544);
    // 5) h2 = LN2(x1)
    ln_kernel<<<MROWS, blk, 0, stream>>>(F1, ln2_g, ln2_b, Abf);
    // 6) t = gelu(h2 @ mlp_w1^T + b1)   [256-wide tile: 9 n-tiles]
    mgemm256<1,1,0,1><<<dim3(9,64), blk, 0, stream>>>(Abf, 544, Wm1, 544, mlp_b1, nullptr, Tb, MROWS, 61, 2176, 544, 2176, nullptr, nullptr);
    // 7) x2 = x1 + t @ mlp_w2^T + b2   [64-tile dbuf]
    mgemm64<0,1,1,0><<<dim3(9,128), blk, 0, stream>>>(Tb, 2176, Wm2, 2176, mlp_b2, F1, F2, MROWS, 122, 544, 2176, 544);
    // 8) h3 = eLN1(x2)
    ln_kernel<<<MROWS, blk, 0, stream>>>(F2, eln1_g, eln1_b, Abf);
    // 9) xu = h3 @ w_trans^T + b_trans   [256-wide tile: 5 n-tiles]
    mgemm256<0,1,0,1><<<dim3(5,64), blk, 0, stream>>>(Abf, 544, Wt, 544, b_trans, nullptr, XU, MROWS, 61, 1088, 544, 1088, nullptr, nullptr);
    // 10/11) s0, s1 fp32 + scatter
    gemm32_kernel<<<dim3(17,1), blk, 0, stream>>>(seed, w0, b0, S0f, NSEED, UPDd, DIMd);
    gemm32_kernel<<<dim3(17,1), blk, 0, stream>>>(seed, w1, b1, S1f, NSEED, UPDd, DIMd);
    scatter_s0big<<<256, blk, 0, stream>>>(S0f, S0big);
    scatter_s1bigT<<<1152, blk, 0, stream>>>(S1f, S1bigT);
    // 12) a = XU @ S0big^T   [64-tile dbuf]
    mgemm64<0,0,0,0><<<dim3(3,128), blk, 0, stream>>>(XU, 1088, S0big, 1088, nullptr, nullptr, a2, MROWS, 122, 136, 1088, 136);
    // 13) softmax over f
    seed_softmax2<<<dim3(136,BSZd), blk, 0, stream>>>(a2);
    // 14) zero mean partials
    zero_kernel<<<3, blk, 0, stream>>>(mean_part, BSZd * NSEED);
    // 15) renorm + mean partials
    seed_renorm<<<dim3(NTOK,BSZd), blk, 0, stream>>>(a2, a2b, mean_part);
    mean_final<<<1, 32, 0, stream>>>(mean_part, mean_attn);
    // 16) o2 = a2b @ S1bigT^T   [256-wide tile: 5 n-tiles, K=160]
    mgemm256<0,0,0,1><<<dim3(5,64), blk, 0, stream>>>(a2b, 160, S1bigT, 160, nullptr, nullptr, O2, MROWS, 61, 1088, 160, 1088, nullptr, nullptr);
    // 17) x3 = x2 + o2 @ w_proj2^T + b_proj2   [64-tile dbuf]
    mgemm64<0,1,1,0><<<dim3(9,128), blk, 0, stream>>>(O2, 1088, Wp2, 1088, b_proj2, F2, F1, MROWS, 122, 544, 1088, 544);
    // 18) h4 = eLN2(x3)
    ln_kernel<<<MROWS, blk, 0, stream>>>(F1, eln2_g, eln2_b, Abf);
    // 19) t2 = gelu(h4 @ emlp_w1^T + b1)   [256-wide tile]
    mgemm256<1,1,0,1><<<dim3(5,64), blk, 0, stream>>>(Abf, 544, We1, 544, emlp_b1, nullptr, T2, MROWS, 61, 1088, 544, 1088, nullptr, nullptr);
    // 20) x4 = x3 + t2 @ emlp_w2^T + b2 -> d_out   [64-tile dbuf]
    mgemm64<0,1,1,0><<<dim3(9,128), blk, 0, stream>>>(T2, 1088, We2, 1088, emlp_b2, F1, xout, MROWS, 122, 544, 1088, 544);
}

// Round 14
// 681.702 us; speedup vs baseline: 1.3258x; 1.3258x over previous
//
#include <hip/hip_runtime.h>
#include <math.h>
#include <stdint.h>

#define BSZd 32
#define NTOK 243
#define DIMd 544
#define NH 8
#define HDd 68
#define NSEED 17
#define UPDd 1088
#define UCd 136
#define MROWS (BSZd*NTOK)          // 7776
#define BND ((size_t)MROWS*DIMd)   // 4230144
#define QPP 24576
#define KPOFF ((size_t)256*QPP)
#define VTP 20480
#define PBP 65536
#define BUFE (128*32)              // 128-tile LDS buffer (attn_pv2)
#define BUFE64 (64*32)             // 64-tile LDS buffer

typedef __bf16 bfx8 __attribute__((ext_vector_type(8)));
typedef __bf16 bfx4 __attribute__((ext_vector_type(4)));
typedef float  fx4  __attribute__((ext_vector_type(4)));

#define GLOAD_LDS(g, l) __builtin_amdgcn_global_load_lds( \
    (__attribute__((address_space(1))) void*)(g), \
    (__attribute__((address_space(3))) void*)(l), 16, 0, 0)

// ========== MFMA core, 128x128 tile, BK=32, 4 waves — double-buffered LDS ==========
// (used only by attn_pv2)
__device__ __forceinline__ void mfma_core(const __bf16* __restrict__ A, int lda,
        const __bf16* __restrict__ W, int ldb, int K,
        __bf16* __restrict__ As, __bf16* __restrict__ Bs, fx4 acc[4][4]) {
    const int tid = threadIdx.x;
    const int lane = tid & 63, wave = tid >> 6;
    const int r = lane >> 2, cp = lane & 3;
    const int c = cp ^ (r & 3) ^ ((r >> 2) & 1);
    const __bf16* Ag0 = A + (size_t)(wave * 32 + r) * lda + c * 8;
    const __bf16* Ag1 = Ag0 + (size_t)16 * lda;
    const __bf16* Wg0 = W + (size_t)(wave * 32 + r) * ldb + c * 8;
    const __bf16* Wg1 = Wg0 + (size_t)16 * ldb;
    const int wr0 = (wave * 32) * 32;
    const int wr1 = (wave * 32 + 16) * 32;
    const int fl = lane & 15, q = lane >> 4;
    const int wm = (wave & 1) * 64, wn = (wave >> 1) * 64;
    const int sw = (fl & 3) ^ ((fl >> 2) & 1);
    const int IT = K >> 5;
    GLOAD_LDS(Ag0, As + wr0);
    GLOAD_LDS(Ag1, As + wr1);
    GLOAD_LDS(Wg0, Bs + wr0);
    GLOAD_LDS(Wg1, Bs + wr1);
    for (int kit = 0; kit < IT; kit++) {
        const int p = kit & 1;
        __syncthreads();
        if (kit + 1 < IT) {
            const int np = 1 - p;
            const int off = (kit + 1) * 32;
            GLOAD_LDS(Ag0 + off, As + np * BUFE + wr0);
            GLOAD_LDS(Ag1 + off, As + np * BUFE + wr1);
            GLOAD_LDS(Wg0 + off, Bs + np * BUFE + wr0);
            GLOAD_LDS(Wg1 + off, Bs + np * BUFE + wr1);
        }
        const __bf16* Ab = As + p * BUFE;
        const __bf16* Bb = Bs + p * BUFE;
        bfx8 af[4], bfr[4];
        #pragma unroll
        for (int i = 0; i < 4; i++) {
            int m = wm + i * 16 + fl;
            af[i] = *(const bfx8*)(Ab + (m * 4 + (q ^ sw)) * 8);
            int n = wn + i * 16 + fl;
            bfr[i] = *(const bfx8*)(Bb + (n * 4 + (q ^ sw)) * 8);
        }
        #pragma unroll
        for (int i = 0; i < 4; i++)
            #pragma unroll
            for (int j = 0; j < 4; j++)
                acc[i][j] = __builtin_amdgcn_mfma_f32_16x16x32_bf16(af[i], bfr[j], acc[i][j], 0, 0, 0);
    }
}

// ---------------- fused weight fp32 -> bf16 ---------
struct Cvt8 {
    const float* src[8];
    __bf16* dst[8];
    int nreal[8];
    int rows[8];
    int K[8];
};
__global__ __launch_bounds__(256) void cvt_all(Cvt8 d) {
    int blk = blockIdx.x;
    int seg = 0, base = 0;
    while (seg < 7 && blk - base >= d.rows[seg]) { base += d.rows[seg]; seg++; }
    int n = blk - base;
    int K = d.K[seg];
    __bf16* drow = d.dst[seg] + (size_t)n * K;
    if (n < d.nreal[seg]) {
        const float* srow = d.src[seg] + (size_t)n * K;
        for (int k = threadIdx.x * 4; k < K; k += 1024) {
            float4 v = *(const float4*)(srow + k);
            bfx4 o; o[0]=(__bf16)v.x; o[1]=(__bf16)v.y; o[2]=(__bf16)v.z; o[3]=(__bf16)v.w;
            *(bfx4*)(drow + k) = o;
        }
    } else {
        bfx4 z = {(__bf16)0.f,(__bf16)0.f,(__bf16)0.f,(__bf16)0.f};
        for (int k = threadIdx.x * 4; k < K; k += 1024) *(bfx4*)(drow + k) = z;
    }
}

// ---------------- zero fill ----------------
__global__ __launch_bounds__(256) void zero4(float4* __restrict__ p, int n4) {
    float4 z = make_float4(0.f, 0.f, 0.f, 0.f);
    for (int i = blockIdx.x * 256 + threadIdx.x; i < n4; i += gridDim.x * 256)
        p[i] = z;
}

// ---------------- LayerNorm fp32 -> bf16 ----------------
__global__ __launch_bounds__(256) void ln_kernel(const float* __restrict__ x,
        const float* __restrict__ g, const float* __restrict__ bb, __bf16* __restrict__ out) {
    int row = blockIdx.x;
    const float* xr = x + (size_t)row * DIMd;
    __bf16* orow = out + (size_t)row * DIMd;
    int tid = threadIdx.x;
    float e0 = xr[tid];
    float e1 = xr[tid + 256];
    float e2 = (tid < DIMd - 512) ? xr[tid + 512] : 0.f;
    float s  = e0 + e1 + e2;
    float sq = e0*e0 + e1*e1 + e2*e2;
    __shared__ float sa[4], sb[4];
    for (int off = 32; off; off >>= 1) { s += __shfl_down(s, off, 64); sq += __shfl_down(sq, off, 64); }
    int lane = tid & 63, w = tid >> 6;
    if (lane == 0) { sa[w] = s; sb[w] = sq; }
    __syncthreads();
    if (tid == 0) { sa[0] = sa[0]+sa[1]+sa[2]+sa[3]; sb[0] = sb[0]+sb[1]+sb[2]+sb[3]; }
    __syncthreads();
    s = sa[0]; sq = sb[0];
    float mean = s * (1.f / DIMd);
    float var  = sq * (1.f / DIMd) - mean * mean;
    float rstd = rsqrtf(var + 1e-5f);
    orow[tid]       = (__bf16)((e0 - mean) * rstd * g[tid]       + bb[tid]);
    orow[tid + 256] = (__bf16)((e1 - mean) * rstd * g[tid + 256] + bb[tid + 256]);
    if (tid < DIMd - 512)
        orow[tid + 512] = (__bf16)((e2 - mean) * rstd * g[tid + 512] + bb[tid + 512]);
}

// ---------- MFMA GEMM (64x64 tile) — high-occupancy, double-buffered LDS ----------
// OUTMODE: 0 = fp32 C, 1 = bf16 C, 2 = qkv scatter into Qp/Kp/Vt panels.
// waves 0,1 stage A; waves 2,3 stage B; 2 global_load_lds/lane/iter; 16KB LDS.
template<int ACT, int HAS_BIAS, int HAS_RES, int OUTMODE>
__global__ __launch_bounds__(256) void mgemm64(
        const __bf16* __restrict__ A, int lda, const __bf16* __restrict__ W, int ldb,
        const float* __restrict__ bias, const float* __restrict__ res,
        void* __restrict__ Cv, int M, int Mtiles, int Nreal, int K, int Cstride,
        __bf16* __restrict__ qQK, __bf16* __restrict__ qVt) {
    const int L = blockIdx.y * gridDim.x + blockIdx.x;
    const int xcd = L & 7, s = L >> 3;
    const int kk2 = s / gridDim.x, j2 = s - kk2 * gridDim.x;
    const int mt = kk2 * 8 + xcd;
    if (mt >= Mtiles) return;
    const int m0 = mt * 64, n0 = j2 * 64;
    __shared__ __bf16 As[2 * BUFE64];
    __shared__ __bf16 Bs[2 * BUFE64];
    const int tid = threadIdx.x, lane = tid & 63, w = tid >> 6;
    const int r = lane >> 2, cp = lane & 3;
    const int c = cp ^ (r & 3);
    const __bf16* G0;
    int ld, wro;
    int isA = (w < 2);
    if (isA) { ld = lda; G0 = A + (size_t)(m0 + w * 32 + r) * lda + c * 8; wro = (w * 32) * 32; }
    else     { ld = ldb; G0 = W + (size_t)(n0 + (w - 2) * 32 + r) * ldb + c * 8; wro = ((w - 2) * 32) * 32; }
    const __bf16* G1 = G0 + (size_t)16 * ld;
    __bf16* base0 = isA ? As : Bs;
    const int wro1 = wro + 16 * 32;
    const int fl = lane & 15, q = lane >> 4;
    const int wm = (w & 1) * 32, wn = (w >> 1) * 32;
    const int sw = fl & 3;
    const int IT = K >> 5;
    fx4 acc[2][2];
    #pragma unroll
    for (int i = 0; i < 2; i++)
        #pragma unroll
        for (int j = 0; j < 2; j++)
            acc[i][j] = (fx4){0.f, 0.f, 0.f, 0.f};
    GLOAD_LDS(G0, base0 + wro);
    GLOAD_LDS(G1, base0 + wro1);
    for (int kit = 0; kit < IT; kit++) {
        const int p = kit & 1;
        __syncthreads();
        if (kit + 1 < IT) {
            const int np = 1 - p;
            const int off = (kit + 1) * 32;
            GLOAD_LDS(G0 + off, base0 + np * BUFE64 + wro);
            GLOAD_LDS(G1 + off, base0 + np * BUFE64 + wro1);
        }
        const __bf16* Ab = As + p * BUFE64;
        const __bf16* Bb = Bs + p * BUFE64;
        bfx8 af[2], bfr[2];
        #pragma unroll
        for (int i = 0; i < 2; i++) {
            int m = wm + i * 16 + fl;
            af[i] = *(const bfx8*)(Ab + (m * 4 + (q ^ sw)) * 8);
            int n = wn + i * 16 + fl;
            bfr[i] = *(const bfx8*)(Bb + (n * 4 + (q ^ sw)) * 8);
        }
        #pragma unroll
        for (int i = 0; i < 2; i++)
            #pragma unroll
            for (int j = 0; j < 2; j++)
                acc[i][j] = __builtin_amdgcn_mfma_f32_16x16x32_bf16(af[i], bfr[j], acc[i][j], 0, 0, 0);
    }
    #pragma unroll
    for (int i = 0; i < 2; i++)
        #pragma unroll
        for (int v = 0; v < 4; v++) {
            int row = m0 + wm + i * 16 + q * 4 + v;
            if (row >= M) continue;
            #pragma unroll
            for (int j = 0; j < 2; j++) {
                int col = n0 + wn + j * 16 + fl;
                if (col >= Nreal) continue;
                float val = acc[i][j][v];
                if (HAS_BIAS) val += bias[col];
                if (ACT == 1) val = 0.5f * val * (1.f + erff(val * 0.70710678118654752f));
                if (HAS_RES)  val += res[(size_t)row * Cstride + col];
                if (OUTMODE == 2) {
                    int t = col / DIMd, rem = col - t * DIMd;
                    int hh = rem / HDd, hd = rem - hh * HDd;
                    int b = row / NTOK, tok = row - b * NTOK;
                    int bh = b * 8 + hh;
                    if (t == 0)      qQK[(size_t)bh * QPP + tok * 96 + hd] = (__bf16)val;
                    else if (t == 1) qQK[KPOFF + (size_t)bh * QPP + tok * 96 + hd] = (__bf16)val;
                    else             qVt[(size_t)bh * VTP + hd * 256 + tok] = (__bf16)val;
                } else if (OUTMODE == 1) {
                    ((__bf16*)Cv)[(size_t)row * Cstride + col] = (__bf16)val;
                } else {
                    ((float*)Cv)[(size_t)row * Cstride + col] = val;
                }
            }
        }
}

// ---------------- fp32 GEMM for tiny seed matmuls (M=17) ----------------
__global__ __launch_bounds__(256) void gemm32_kernel(
        const float* __restrict__ A, const float* __restrict__ W,
        const float* __restrict__ bias, float* __restrict__ C, int M, int Nn, int K) {
    __shared__ __align__(16) float As[16][68];
    __shared__ __align__(16) float Ws[16][68];
    int tid = threadIdx.x;
    int tx = tid & 15, ty = tid >> 4;
    int m0 = blockIdx.y * 64, n0 = blockIdx.x * 64;
    float acc[4][4] = {};
    int lr = tid >> 2, lk = (tid & 3) << 2;
    for (int k0 = 0; k0 < K; k0 += 16) {
        float4 av = make_float4(0.f,0.f,0.f,0.f), wv = make_float4(0.f,0.f,0.f,0.f);
        int gm = m0 + lr, gn = n0 + lr, gk = k0 + lk;
        if (gm < M)  av = *(const float4*)(A + (size_t)gm * K + gk);
        if (gn < Nn) wv = *(const float4*)(W + (size_t)gn * K + gk);
        __syncthreads();
        As[lk+0][lr]=av.x; As[lk+1][lr]=av.y; As[lk+2][lr]=av.z; As[lk+3][lr]=av.w;
        Ws[lk+0][lr]=wv.x; Ws[lk+1][lr]=wv.y; Ws[lk+2][lr]=wv.z; Ws[lk+3][lr]=wv.w;
        __syncthreads();
        #pragma unroll
        for (int kk = 0; kk < 16; kk++) {
            float4 a4 = *(const float4*)&As[kk][ty << 2];
            float4 b4 = *(const float4*)&Ws[kk][tx << 2];
            float ar[4] = {a4.x, a4.y, a4.z, a4.w};
            float br[4] = {b4.x, b4.y, b4.z, b4.w};
            #pragma unroll
            for (int i = 0; i < 4; i++)
                #pragma unroll
                for (int j = 0; j < 4; j++)
                    acc[i][j] = fmaf(ar[i], br[j], acc[i][j]);
        }
    }
    #pragma unroll
    for (int i = 0; i < 4; i++) {
        int gm = m0 + (ty << 2) + i;
        if (gm >= M) continue;
        #pragma unroll
        for (int j = 0; j < 4; j++) {
            int gn = n0 + (tx << 2) + j;
            if (gn >= Nn) continue;
            C[(size_t)gm * Nn + gn] = acc[i][j] + bias[gn];
        }
    }
}

// ================= ATTENTION kernel A: E = exp(QK^T*scale+bias), row sums =========
__global__ __launch_bounds__(256) void attn_escore(const __bf16* __restrict__ Qp,
        const float* __restrict__ bt, __bf16* __restrict__ Pb, float* __restrict__ rs) {
    __shared__ __bf16 Qs[128 * 96];
    __shared__ __bf16 Ks[256 * 96];
    __shared__ float sumb[128 * 2];
    const int mh = blockIdx.x, bh = blockIdx.y, h = bh & 7;
    const int tid = threadIdx.x, lane = tid & 63, w = tid >> 6;
    const int fl = lane & 15, q = lane >> 4;
    const int wm = (w & 1) * 64, wn = (w >> 1) * 128;
    const __bf16* Qg = Qp + (size_t)bh * QPP + (size_t)mh * 128 * 96;
    const __bf16* Kg = Qp + KPOFF + (size_t)bh * QPP;
    #pragma unroll
    for (int it = 0; it < 6; it++) {
        int Lc = (w * 6 + it) * 64 + lane;
        int r = Lc / 12, sl = Lc - r * 12, c = sl ^ (r & 3);
        GLOAD_LDS(Qg + r * 96 + c * 8, Qs + Lc * 8);
    }
    #pragma unroll
    for (int it = 0; it < 12; it++) {
        int Lc = (w * 12 + it) * 64 + lane;
        int r = Lc / 12, sl = Lc - r * 12, c = sl ^ (r & 3);
        GLOAD_LDS(Kg + r * 96 + c * 8, Ks + Lc * 8);
    }
    __syncthreads();
    fx4 acc[4][8];
    #pragma unroll
    for (int i = 0; i < 4; i++)
        #pragma unroll
        for (int jj = 0; jj < 8; jj++)
            acc[i][jj] = (fx4){0.f, 0.f, 0.f, 0.f};
    #pragma unroll
    for (int kk = 0; kk < 3; kk++) {
        bfx8 af[4], bfr[8];
        #pragma unroll
        for (int i = 0; i < 4; i++) {
            int rA = wm + i * 16 + fl, cA = kk * 4 + q;
            af[i] = *(const bfx8*)(Qs + (rA * 12 + (cA ^ (rA & 3))) * 8);
        }
        #pragma unroll
        for (int jj = 0; jj < 8; jj++) {
            int rB = wn + jj * 16 + fl, cB = kk * 4 + q;
            bfr[jj] = *(const bfx8*)(Ks + (rB * 12 + (cB ^ (rB & 3))) * 8);
        }
        #pragma unroll
        for (int i = 0; i < 4; i++)
            #pragma unroll
            for (int jj = 0; jj < 8; jj++)
                acc[i][jj] = __builtin_amdgcn_mfma_f32_16x16x32_bf16(af[i], bfr[jj], acc[i][jj], 0, 0, 0);
    }
    const float scale = 0.121267812518166f;
    const float* btr = bt + h * (2 * NTOK - 1);
    __bf16* Pp = Pb + (size_t)bh * PBP + (size_t)mh * 128 * 256;
    #pragma unroll
    for (int i = 0; i < 4; i++)
        #pragma unroll
        for (int v = 0; v < 4; v++) {
            int lr = wm + i * 16 + q * 4 + v;
            int gm = mh * 128 + lr;
            float sm = 0.f;
            #pragma unroll
            for (int jj = 0; jj < 8; jj++) {
                int gn = wn + jj * 16 + fl;
                float e = 0.f;
                if (gm < NTOK && gn < NTOK)
                    e = expf(acc[i][jj][v] * scale + btr[gm - gn + NTOK - 1]);
                acc[i][jj][v] = e;
                sm += e;
                Pp[(size_t)lr * 256 + gn] = (__bf16)e;
            }
            #pragma unroll
            for (int msk = 1; msk < 16; msk <<= 1)
                sm += __shfl_xor(sm, msk, 64);
            if (fl == 0) sumb[lr * 2 + (w >> 1)] = sm;
        }
    __syncthreads();
    if (tid < 128)
        rs[(size_t)bh * 256 + mh * 128 + tid] = sumb[tid * 2] + sumb[tid * 2 + 1];
}

// ================= ATTENTION kernel B: O = (E @ V) / rowsum =================
__global__ __launch_bounds__(256) void attn_pv2(const __bf16* __restrict__ Pb,
        const __bf16* __restrict__ Vt, const float* __restrict__ rs,
        __bf16* __restrict__ o) {
    __shared__ __bf16 As[2 * BUFE];
    __shared__ __bf16 Bs[2 * BUFE];
    const int mt = blockIdx.x, bh = blockIdx.y, b = bh >> 3, h = bh & 7;
    const int tid = threadIdx.x, lane = tid & 63, wave = tid >> 6;
    fx4 acc[4][4];
    #pragma unroll
    for (int i = 0; i < 4; i++)
        #pragma unroll
        for (int j = 0; j < 4; j++)
            acc[i][j] = (fx4){0.f, 0.f, 0.f, 0.f};
    mfma_core(Pb + (size_t)bh * PBP + (size_t)mt * 128 * 256, 256,
              Vt + (size_t)bh * VTP, 256, 256, As, Bs, acc);
    const int fl = lane & 15, q = lane >> 4;
    const int wm = (wave & 1) * 64, wn = (wave >> 1) * 64;
    #pragma unroll
    for (int i = 0; i < 4; i++)
        #pragma unroll
        for (int v = 0; v < 4; v++) {
            int gm = mt * 128 + wm + i * 16 + q * 4 + v;
            if (gm >= NTOK) continue;
            float inv = 1.f / rs[(size_t)bh * 256 + gm];
            #pragma unroll
            for (int j = 0; j < 4; j++) {
                int col = wn + j * 16 + fl;
                if (col >= HDd) continue;
                o[((size_t)(b * NTOK + gm)) * DIMd + h * HDd + col] = (__bf16)(acc[i][j][v] * inv);
            }
        }
}

// ---------------- seed scatters ----------------
__global__ __launch_bounds__(256) void scatter_s0big(const float* __restrict__ S0f,
        __bf16* __restrict__ W) {
    int hn = blockIdx.x;
    __bf16* row = W + (size_t)hn * UPDd;
    int h = hn / NSEED, n = hn - h * NSEED;
    for (int j = threadIdx.x; j < UPDd; j += 256) {
        __bf16 v = (__bf16)0.f;
        if (hn < 136 && (j / UCd) == h) v = (__bf16)S0f[(size_t)n * UPDd + j];
        row[j] = v;
    }
}

__global__ __launch_bounds__(256) void scatter_s1bigT(const float* __restrict__ S1f,
        __bf16* __restrict__ W) {
    int j = blockIdx.x;
    __bf16* row = W + (size_t)j * 160;
    int hj = j / UCd;
    int t = threadIdx.x;
    if (t < 160) {
        __bf16 v = (__bf16)0.f;
        if (j < UPDd && t < 136) {
            int h = t / NSEED, n = t - h * NSEED;
            if (h == hj) v = (__bf16)S1f[(size_t)n * UPDd + j];
        }
        row[t] = v;
    }
}

// seed: column softmax over f
__global__ __launch_bounds__(256) void seed_softmax2(float* __restrict__ a2) {
    int col = blockIdx.x, b = blockIdx.y;
    float* base = a2 + (size_t)b * NTOK * 136 + col;
    int f = threadIdx.x;
    __shared__ float rbuf[4];
    float v = (f < NTOK) ? base[(size_t)f * 136] : -1e30f;
    float m = v;
    for (int off = 32; off; off >>= 1) m = fmaxf(m, __shfl_down(m, off, 64));
    int lane = f & 63, w = f >> 6;
    if (lane == 0) rbuf[w] = m;
    __syncthreads();
    m = fmaxf(fmaxf(rbuf[0], rbuf[1]), fmaxf(rbuf[2], rbuf[3]));
    float e = (f < NTOK) ? expf(v - m) : 0.f;
    float s = e;
    for (int off = 32; off; off >>= 1) s += __shfl_down(s, off, 64);
    __syncthreads();
    if (lane == 0) rbuf[w] = s;
    __syncthreads();
    float denom = rbuf[0] + rbuf[1] + rbuf[2] + rbuf[3];
    if (f < NTOK) base[(size_t)f * 136] = e / denom;
}

__global__ void zero_kernel(float* p, int n) {
    int i = blockIdx.x * blockDim.x + threadIdx.x;
    if (i < n) p[i] = 0.f;
}

// seed: renorm over n per (b,f) -> bf16 a2b, per-b mean partials
__global__ __launch_bounds__(256) void seed_renorm(const float* __restrict__ a2,
        __bf16* __restrict__ a2b, float* __restrict__ part) {
    int f = blockIdx.x, b = blockIdx.y;
    int t = threadIdx.x;
    __shared__ float vals[136];
    __shared__ float hinv[8];
    __shared__ float nsum[NSEED];
    if (t < NSEED) nsum[t] = 0.f;
    const float* arow = a2 + ((size_t)(b * NTOK + f)) * 136;
    if (t < 136) vals[t] = arow[t];
    __syncthreads();
    if (t < 8) {
        float s = 0.f;
        #pragma unroll
        for (int n = 0; n < NSEED; n++) s += vals[t * NSEED + n];
        hinv[t] = 1.f / (1e-7f + s);
    }
    __syncthreads();
    __bf16* brow = a2b + ((size_t)(b * NTOK + f)) * 160;
    if (t < 160) {
        if (t < 136) {
            float wv = vals[t] * hinv[t / NSEED];
            brow[t] = (__bf16)wv;
            atomicAdd(&nsum[t % NSEED], wv);
        } else brow[t] = (__bf16)0.f;
    }
    __syncthreads();
    if (t < NSEED) atomicAdd(&part[b * NSEED + t], nsum[t]);
}

__global__ void mean_final(const float* __restrict__ part, float* __restrict__ mean_attn) {
    int n = threadIdx.x;
    if (n < NSEED) {
        float s = 0.f;
        for (int b = 0; b < BSZd; b++) s += part[b * NSEED + n];
        mean_attn[n] = s * (1.f / (BSZd * NH * NTOK));
    }
}

extern "C" void kernel_launch(void* const* d_in, const int* in_sizes, int n_in,
                              void* d_out, int out_size, void* d_ws, size_t ws_size,
                              hipStream_t stream) {
    (void)in_sizes; (void)n_in; (void)out_size; (void)ws_size;
    const float* x       = (const float*)d_in[0];
    const float* seed    = (const float*)d_in[1];
    const float* ln1_g   = (const float*)d_in[2];
    const float* ln1_b   = (const float*)d_in[3];
    const float* w_qkv   = (const float*)d_in[4];
    const float* w_proj  = (const float*)d_in[5];
    const float* b_proj  = (const float*)d_in[6];
    const float* b_table = (const float*)d_in[7];
    const float* ln2_g   = (const float*)d_in[8];
    const float* ln2_b   = (const float*)d_in[9];
    const float* mlp_w1  = (const float*)d_in[10];
    const float* mlp_b1  = (const float*)d_in[11];
    const float* mlp_w2  = (const float*)d_in[12];
    const float* mlp_b2  = (const float*)d_in[13];
    const float* eln1_g  = (const float*)d_in[14];
    const float* eln1_b  = (const float*)d_in[15];
    const float* w_trans = (const float*)d_in[16];
    const float* b_trans = (const float*)d_in[17];
    const float* w0      = (const float*)d_in[18];
    const float* b0      = (const float*)d_in[19];
    const float* w1      = (const float*)d_in[20];
    const float* b1      = (const float*)d_in[21];
    const float* w_proj2 = (const float*)d_in[22];
    const float* b_proj2 = (const float*)d_in[23];
    const float* eln2_g  = (const float*)d_in[24];
    const float* eln2_b  = (const float*)d_in[25];
    const float* emlp_w1 = (const float*)d_in[26];
    const float* emlp_b1 = (const float*)d_in[27];
    const float* emlp_w2 = (const float*)d_in[28];
    const float* emlp_b2 = (const float*)d_in[29];

    // ---- workspace layout (bytes) ----
    char* wsb = (char*)d_ws;
    __bf16* Wq  = (__bf16*)(wsb);               // [1664][544]
    __bf16* Wp  = (__bf16*)(wsb + 1810432);     // [640][544]
    __bf16* Wm1 = (__bf16*)(wsb + 2506752);     // [2176][544]
    __bf16* Wm2 = (__bf16*)(wsb + 4874240);     // [640][2176]
    __bf16* Wt  = (__bf16*)(wsb + 7659520);     // [1152][544]
    __bf16* Wp2 = (__bf16*)(wsb + 8912896);     // [640][1088]
    __bf16* We1 = (__bf16*)(wsb + 10305536);    // [1152][544]
    __bf16* We2 = (__bf16*)(wsb + 11558912);    // [640][1088]
    __bf16* Abf = (__bf16*)(wsb + 12951552);    // [7808][544]
    float*  F1  = (float*) (wsb + 21446656);    // [7776][544] fp32
    float*  F2  = (float*) (wsb + 38367232);    // [7776][544] fp32
    char*   RegBig = wsb + 55287808;            // 33,978,368 B
    char*   RegS   = wsb + 89266176;            // 15,178,752 B
    // attention overlays:
    __bf16* Qp  = (__bf16*)RegBig;              // Q/K panels
    __bf16* Pb  = (__bf16*)F1;                  // E panels (F1+F2)
    __bf16* Vt  = (__bf16*)RegS;                // V panels (10.49MB)
    float*  rsb = (float*)(RegS + 10485760);    // rowsums
    // other phase overlays:
    __bf16* Tb   = (__bf16*)RegBig;             // [7808][2176]
    __bf16* XU   = (__bf16*)RegBig;             // [7776][1088]
    __bf16* O2   = (__bf16*)(RegBig + 16920576);// [7808][1088]
    __bf16* T2   = (__bf16*)RegBig;             // [7808][1088]
    float*  a2    = (float*)RegS;               // [7776][136]
    __bf16* a2b   = (__bf16*)(RegS + 4230144);  // [7808][160]
    float*  S0f   = (float*)(RegS + 6728704);
    float*  S1f   = (float*)(RegS + 6802688);
    __bf16* S0big = (__bf16*)(RegS + 6876672);  // [256][1088]
    __bf16* S1bigT= (__bf16*)(RegS + 7433728);  // [1152][160]
    float*  mean_part = (float*)(RegS + 7802368);
    float* xout = (float*)d_out;
    float* mean_attn = xout + BND;

    dim3 blk(256);
    // 0) fused weight conversion
    Cvt8 cd;
    cd.src[0]=w_qkv;  cd.dst[0]=Wq;  cd.nreal[0]=1632; cd.rows[0]=1664; cd.K[0]=544;
    cd.src[1]=w_proj; cd.dst[1]=Wp;  cd.nreal[1]=544;  cd.rows[1]=640;  cd.K[1]=544;
    cd.src[2]=mlp_w1; cd.dst[2]=Wm1; cd.nreal[2]=2176; cd.rows[2]=2176; cd.K[2]=544;
    cd.src[3]=mlp_w2; cd.dst[3]=Wm2; cd.nreal[3]=544;  cd.rows[3]=640;  cd.K[3]=2176;
    cd.src[4]=w_trans;cd.dst[4]=Wt;  cd.nreal[4]=1088; cd.rows[4]=1152; cd.K[4]=544;
    cd.src[5]=w_proj2;cd.dst[5]=Wp2; cd.nreal[5]=544;  cd.rows[5]=640;  cd.K[5]=1088;
    cd.src[6]=emlp_w1;cd.dst[6]=We1; cd.nreal[6]=1088; cd.rows[6]=1152; cd.K[6]=544;
    cd.src[7]=emlp_w2;cd.dst[7]=We2; cd.nreal[7]=544;  cd.rows[7]=640;  cd.K[7]=1088;
    cvt_all<<<8704, blk, 0, stream>>>(cd);
    // 0b) zero Q/K and V panels (pads)
    zero4<<<1024, blk, 0, stream>>>((float4*)Qp, 1572864);
    zero4<<<1024, blk, 0, stream>>>((float4*)Vt, 655360);
    // 1) h = LN1(x)
    ln_kernel<<<MROWS, blk, 0, stream>>>(x, ln1_g, ln1_b, Abf);
    // 2) qkv -> Qp/Kp/Vt panels   [64-tile dbuf, 26x122 useful blocks]
    mgemm64<0,0,0,2><<<dim3(26,128), blk, 0, stream>>>(Abf, 544, Wq, 544, nullptr, nullptr, nullptr, MROWS, 122, 1632, 544, 0, Qp, Vt);
    // 3) attention: E-score + PV
    attn_escore<<<dim3(2,256), blk, 0, stream>>>(Qp, b_table, Pb, rsb);
    attn_pv2<<<dim3(2,256), blk, 0, stream>>>(Pb, Vt, rsb, Abf);
    // 4) x1 = x + o @ w_proj^T + b_proj   [64-tile dbuf]
    mgemm64<0,1,1,0><<<dim3(9,128), blk, 0, stream>>>(Abf, 544, Wp, 544, b_proj, x, F1, MROWS, 122, 544, 544, 544, nullptr, nullptr);
    // 5) h2 = LN2(x1)
    ln_kernel<<<MROWS, blk, 0, stream>>>(F1, ln2_g, ln2_b, Abf);
    // 6) t = gelu(h2 @ mlp_w1^T + b1)   [64-tile dbuf, 34x122 blocks]
    mgemm64<1,1,0,1><<<dim3(34,128), blk, 0, stream>>>(Abf, 544, Wm1, 544, mlp_b1, nullptr, Tb, MROWS, 122, 2176, 544, 2176, nullptr, nullptr);
    // 7) x2 = x1 + t @ mlp_w2^T + b2   [64-tile dbuf]
    mgemm64<0,1,1,0><<<dim3(9,128), blk, 0, stream>>>(Tb, 2176, Wm2, 2176, mlp_b2, F1, F2, MROWS, 122, 544, 2176, 544, nullptr, nullptr);
    // 8) h3 = eLN1(x2)
    ln_kernel<<<MROWS, blk, 0, stream>>>(F2, eln1_g, eln1_b, Abf);
    // 9) xu = h3 @ w_trans^T + b_trans   [64-tile dbuf, 17x122]
    mgemm64<0,1,0,1><<<dim3(17,128), blk, 0, stream>>>(Abf, 544, Wt, 544, b_trans, nullptr, XU, MROWS, 122, 1088, 544, 1088, nullptr, nullptr);
    // 10/11) s0, s1 fp32 + scatter
    gemm32_kernel<<<dim3(17,1), blk, 0, stream>>>(seed, w0, b0, S0f, NSEED, UPDd, DIMd);
    gemm32_kernel<<<dim3(17,1), blk, 0, stream>>>(seed, w1, b1, S1f, NSEED, UPDd, DIMd);
    scatter_s0big<<<256, blk, 0, stream>>>(S0f, S0big);
    scatter_s1bigT<<<1152, blk, 0, stream>>>(S1f, S1bigT);
    // 12) a = XU @ S0big^T   [64-tile dbuf]
    mgemm64<0,0,0,0><<<dim3(3,128), blk, 0, stream>>>(XU, 1088, S0big, 1088, nullptr, nullptr, a2, MROWS, 122, 136, 1088, 136, nullptr, nullptr);
    // 13) softmax over f
    seed_softmax2<<<dim3(136,BSZd), blk, 0, stream>>>(a2);
    // 14) zero mean partials
    zero_kernel<<<3, blk, 0, stream>>>(mean_part, BSZd * NSEED);
    // 15) renorm + mean partials
    seed_renorm<<<dim3(NTOK,BSZd), blk, 0, stream>>>(a2, a2b, mean_part);
    mean_final<<<1, 32, 0, stream>>>(mean_part, mean_attn);
    // 16) o2 = a2b @ S1bigT^T   [64-tile dbuf, K=160, 17x122]
    mgemm64<0,0,0,1><<<dim3(17,128), blk, 0, stream>>>(a2b, 160, S1bigT, 160, nullptr, nullptr, O2, MROWS, 122, 1088, 160, 1088, nullptr, nullptr);
    // 17) x3 = x2 + o2 @ w_proj2^T + b_proj2   [64-tile dbuf]
    mgemm64<0,1,1,0><<<dim3(9,128), blk, 0, stream>>>(O2, 1088, Wp2, 1088, b_proj2, F2, F1, MROWS, 122, 544, 1088, 544, nullptr, nullptr);
    // 18) h4 = eLN2(x3)
    ln_kernel<<<MROWS, blk, 0, stream>>>(F1, eln2_g, eln2_b, Abf);
    // 19) t2 = gelu(h4 @ emlp_w1^T + b1)   [64-tile dbuf]
    mgemm64<1,1,0,1><<<dim3(17,128), blk, 0, stream>>>(Abf, 544, We1, 544, emlp_b1, nullptr, T2, MROWS, 122, 1088, 544, 1088, nullptr, nullptr);
    // 20) x4 = x3 + t2 @ emlp_w2^T + b2 -> d_out   [64-tile dbuf]
    mgemm64<0,1,1,0><<<dim3(9,128), blk, 0, stream>>>(T2, 1088, We2, 1088, emlp_b2, F1, xout, MROWS, 122, 544, 1088, 544, nullptr, nullptr);
}